// Round 4
// baseline (146.563 us; speedup 1.0000x reference)
//
#include <hip/hip_runtime.h>
#include <stdint.h>

// MSA fused kernel: qkv = z @ W^T ; split heads ; flash attention ; out fp32.
// R7 -> R8 (attention only):
//  (a) sP bank conflicts (2.1M cycles, exactly 4cyc x 4writes x 32it x 4w x 1024blk)
//      fixed: slot map X = h ^ ((l15>>1)&7) is a full bijection within each
//      16-lane quarter; P read as two ds_read_b64 (drops the b128 pair
//      constraint that pinned the low slot bit). Write AND read now at HW min.
//  (b) KVBLK 64 -> 32: LDS 40 KB -> 20 KB => 8 blocks/CU = 32 waves/CU (100%).
//      Chain segments halve, 2x waves hide the (unsaturated-pipe) latency.
//      lsum/acc accumulation order preserved -> bit-identical numerics.

typedef _Float16 f16x8 __attribute__((ext_vector_type(8)));
typedef float f32x4 __attribute__((ext_vector_type(4)));
typedef unsigned short u16x8 __attribute__((ext_vector_type(8)));
typedef unsigned short u16x4 __attribute__((ext_vector_type(4)));

#define MFMA_F16(A, B, C) __builtin_amdgcn_mfma_f32_16x16x32_f16((A), (B), (C), 0, 0, 0)

__device__ __forceinline__ unsigned short f2h(float f) {
  _Float16 h = (_Float16)f;  // hw RNE cvt
  return __builtin_bit_cast(unsigned short, h);
}
__device__ __forceinline__ float h2f(unsigned short s) {
  return (float)__builtin_bit_cast(_Float16, s);
}
__device__ __forceinline__ f16x8 ldh8(const unsigned short* p) {
  return __builtin_bit_cast(f16x8, *(const u16x8*)p);
}
// async global->LDS, 16B per lane; dest must be wave-uniform (HW adds lane*16)
__device__ __forceinline__ void lds16(const void* g, void* l) {
  __builtin_amdgcn_global_load_lds((const __attribute__((address_space(1))) void*)g,
                                   (__attribute__((address_space(3))) void*)l,
                                   16, 0, 0);
}

// ---------------- fp32 -> (hi, lo) fp16 split (for z) ----------------
__global__ __launch_bounds__(256) void split_kernel(const float* __restrict__ src,
                                                    unsigned short* __restrict__ hi,
                                                    unsigned short* __restrict__ lo,
                                                    int n4) {
  int i = blockIdx.x * 256 + threadIdx.x;
  if (i >= n4) return;
  const float4 v = reinterpret_cast<const float4*>(src)[i];
  float vv[4] = {v.x, v.y, v.z, v.w};
  unsigned short hh[4], ll[4];
#pragma unroll
  for (int j = 0; j < 4; j++) {
    hh[j] = f2h(vv[j]);
    ll[j] = f2h(vv[j] - h2f(hh[j]));
  }
  u16x4 hv = {hh[0], hh[1], hh[2], hh[3]};
  u16x4 lv = {ll[0], ll[1], ll[2], ll[3]};
  *(u16x4*)&hi[i * 4] = hv;
  *(u16x4*)&lo[i * 4] = lv;
}

// ---------------- fp32 -> fp16 convert (for W, hi only) ----------------
__global__ __launch_bounds__(256) void conv_kernel(const float* __restrict__ src,
                                                   unsigned short* __restrict__ dst,
                                                   int n4) {
  int i = blockIdx.x * 256 + threadIdx.x;
  if (i >= n4) return;
  const float4 v = reinterpret_cast<const float4*>(src)[i];
  u16x4 hv = {f2h(v.x), f2h(v.y), f2h(v.z), f2h(v.w)};
  *(u16x4*)&dst[i * 4] = hv;
}

// ---------------- QKV GEMM: C[4096][3072] = Z @ W^T, scattered epilogue ----------------
// grid (32, 24), 256 threads (4 waves, 2x2, wave-tile 64x64), BK=64.
// LDS tiles [128][64] fp16, XOR chunk-swizzled: 16B-chunk c of row r at (c ^ (r&7)),
// staged via pre-swizzled global source (linear LDS dest).
__global__ __launch_bounds__(256) void qkv_gemm(
    const unsigned short* __restrict__ Ah, const unsigned short* __restrict__ Al,
    const unsigned short* __restrict__ Wh,
    unsigned short* __restrict__ qh, unsigned short* __restrict__ ql,
    unsigned short* __restrict__ kk, unsigned short* __restrict__ vt) {
  __shared__ unsigned short sAh[128 * 64], sAl[128 * 64], sBh[128 * 64];
  const int tid = threadIdx.x;
  const int w = tid >> 6, l = tid & 63;
  const int wr = w >> 1, wc = w & 1;
  const int l15 = l & 15, l4 = l >> 4;
  const int swz = l15 & 7;
  const int bm = blockIdx.x, bn = blockIdx.y;

  f32x4 acc[4][4];
#pragma unroll
  for (int i = 0; i < 4; i++)
#pragma unroll
    for (int j = 0; j < 4; j++) acc[i][j] = (f32x4){0.f, 0.f, 0.f, 0.f};

  for (int k0 = 0; k0 < 1024; k0 += 64) {
    __syncthreads();
#pragma unroll
    for (int c = 0; c < 4; c++) {
      const int chunk = tid + c * 256;          // 0..1023: row = chunk/8, chunk-in-row = chunk%8
      const int row = chunk >> 3, cc = chunk & 7;
      const int scc = cc ^ (row & 7);           // pre-swizzled source chunk
      const int aoff = (bm * 128 + row) * 1024 + k0 + scc * 8;
      const int boff = (bn * 128 + row) * 1024 + k0 + scc * 8;
      const int lo = (w * 64 + c * 256) * 8;    // wave-uniform linear LDS dest
      lds16(Ah + aoff, sAh + lo);
      lds16(Al + aoff, sAl + lo);
      lds16(Wh + boff, sBh + lo);
    }
    __syncthreads();

#pragma unroll
    for (int kh2 = 0; kh2 < 2; kh2++) {
      f16x8 afh[4], afl[4], bfr[4];
#pragma unroll
      for (int i = 0; i < 4; i++) {
        const int off = (wr * 64 + i * 16 + l15) * 64 + ((kh2 * 4 + l4) ^ swz) * 8;
        afh[i] = ldh8(sAh + off);
        afl[i] = ldh8(sAl + off);
      }
#pragma unroll
      for (int j = 0; j < 4; j++) {
        const int off = (wc * 64 + j * 16 + l15) * 64 + ((kh2 * 4 + l4) ^ swz) * 8;
        bfr[j] = ldh8(sBh + off);
      }
      __builtin_amdgcn_s_setprio(1);
#pragma unroll
      for (int i = 0; i < 4; i++)
#pragma unroll
        for (int j = 0; j < 4; j++) {
          acc[i][j] = MFMA_F16(afh[i], bfr[j], acc[i][j]);
          acc[i][j] = MFMA_F16(afl[i], bfr[j], acc[i][j]);
        }
      __builtin_amdgcn_s_setprio(0);
    }
  }

  // epilogue: scatter into q(hi,lo, *0.125*log2e), k(hi), v^T — all fp16
#pragma unroll
  for (int i = 0; i < 4; i++)
#pragma unroll
    for (int j = 0; j < 4; j++)
#pragma unroll
      for (int r = 0; r < 4; r++) {
        float val = acc[i][j][r];
        const int m = bm * 128 + wr * 64 + i * 16 + l4 * 4 + r;
        const int e = bn * 128 + wc * 64 + j * 16 + l15;
        const int b = m >> 11, nidx = m & 2047;
        const int head = e / 192;
        const int rem = e - head * 192;
        const int which = rem >> 6, dh = rem & 63;
        const int bh = b * 16 + head;
        if (which == 0) {
          // 0.125 * log2(e): scores come out in log2 domain -> attn uses exp2
          const float v = val * 0.18033688011112042f;
          const unsigned short h = f2h(v);
          const int o = (bh * 2048 + nidx) * 64 + dh;
          qh[o] = h;
          ql[o] = f2h(v - h2f(h));
        } else if (which == 1) {
          kk[(bh * 2048 + nidx) * 64 + dh] = f2h(val);
        } else {
          vt[(bh * 64 + dh) * 2048 + nidx] = f2h(val);
        }
      }
}

// ---------------- flash attention (no-max softmax, dbuf staging, KVBLK=32) ----------
// grid (n/64, b*h) = (32, 32), 256 threads (4 waves); wave w owns q rows
// [q0 + 16w, q0 + 16w + 16). LDS 20 KB -> 8 blocks/CU (32 waves/CU, 100%).
// SWAPPED QK^T: S^T = mfma(K, Q) -> lane holds P[q=l15][kv=16t+4*l4+r], t=0..1.
// sP slot map X = h ^ ((l15>>1)&7): full bijection per quarter-wave -> zero
// bank conflicts on write (b64) and read (2x b64). P,V fp16.
__global__ __launch_bounds__(256, 8) void attn_kernel(
    const unsigned short* __restrict__ qh, const unsigned short* __restrict__ ql,
    const unsigned short* __restrict__ kk,
    const unsigned short* __restrict__ vt, float* __restrict__ out) {
  __shared__ unsigned short sK[2][32 * 64], sV[2][64 * 32];
  __shared__ unsigned short sP[4][16 * 32];  // per-wave P tile (16 q x 32 kv)
  const int tid = threadIdx.x, w = tid >> 6, l = tid & 63;
  const int l15 = l & 15, l4 = l >> 4;
  const int swz = l15 & 7;         // sK read swizzle (row&7 == l15&7)
  const int swv = (l15 >> 1) & 3;  // sV read swizzle ((row>>1)&3 == (l15>>1)&3)
  const int swp = (l15 >> 1) & 7;  // sP slot bijection key
  const int bh = blockIdx.y;
  const int q0 = blockIdx.x * 64;

  // Q fragments (hi/lo), q pre-scaled by 0.125*log2e
  f16x8 qfh[2], qfl[2];
  {
    const int qrow = (bh * 2048 + q0 + w * 16 + l15) * 64;
#pragma unroll
    for (int kf = 0; kf < 2; kf++) {
      qfh[kf] = ldh8(qh + qrow + kf * 32 + l4 * 8);
      qfl[kf] = ldh8(ql + qrow + kf * 32 + l4 * 8);
    }
  }

  float lsum = 0.f;  // denominator partial for q = l15 (this lane's kv slice)
  f32x4 acc[4];
#pragma unroll
  for (int t = 0; t < 4; t++) acc[t] = (f32x4){0.f, 0.f, 0.f, 0.f};

  const unsigned short* kb = kk + bh * 2048 * 64;
  const unsigned short* vb = vt + bh * 64 * 2048;

  // K tile [32 kv][64 d] = 4 KB; V^T tile [64 d][32 kv] = 4 KB. One lds16/wave each.
  auto STAGE = [&](int bb, int kv0) {
    const int krow = w * 8 + (l >> 3);               // 8 rows per wave
    const int kcc = (l & 7) ^ (krow & 7);            // pre-swizzled source chunk
    lds16(kb + (kv0 + krow) * 64 + kcc * 8, &sK[bb][w * 512]);
    const int vrow = w * 16 + (l >> 2);              // 16 rows per wave
    const int vcc = (l & 3) ^ ((vrow >> 1) & 3);     // pre-swizzled source chunk
    lds16(vb + vrow * 2048 + kv0 + vcc * 8, &sV[bb][w * 512]);
  };

  STAGE(0, 0);
  __syncthreads();

  for (int it = 0; it < 64; ++it) {
    const int cur = it & 1;
    if (it < 63) STAGE(cur ^ 1, (it + 1) * 32);  // prefetch next tile (in flight)

    // S^T = K Q^T (2-term hi/lo): A = K (rows = kv), B = Q (cols = q)
    // lane: q = l15, kv = 16t + 4*l4 + r, t = 0..1
    f32x4 s[2];
    __builtin_amdgcn_s_setprio(1);
#pragma unroll
    for (int t = 0; t < 2; t++) {
      f32x4 z0 = (f32x4){0.f, 0.f, 0.f, 0.f};
#pragma unroll
      for (int kf = 0; kf < 2; kf++) {
        const int off = (t * 16 + l15) * 64 + ((kf * 4 + l4) ^ swz) * 8;
        const f16x8 kh8 = ldh8(&sK[cur][off]);
        z0 = MFMA_F16(kh8, qfh[kf], z0);
        z0 = MFMA_F16(kh8, qfl[kf], z0);
      }
      s[t] = z0;
    }
    __builtin_amdgcn_s_setprio(0);

    // softmax-lite: p = exp2(s) (log2e pre-folded), no max-shift, deferred denom.
    // Lane writes its 4-run at slot h = 4t+l4, physical X = h ^ swp (bijective
    // per quarter: 16 lanes -> 16 distinct bank-pairs).
#pragma unroll
    for (int t = 0; t < 2; t++) {
      u16x4 pv;
#pragma unroll
      for (int r = 0; r < 4; r++) {
        const float p = __builtin_amdgcn_exp2f(s[t][r]);
        const unsigned short us = f2h(p);
        pv[r] = us;
        lsum += h2f(us);  // denominator consistent with rounded numerator
      }
      const int X = (4 * t + l4) ^ swp;
      *(u16x4*)&sP[w][l15 * 32 + X * 4] = pv;
    }

    // PV: O += P @ V  (k = 32: single A-fragment, read as two b64 at X0, X0^1)
    __builtin_amdgcn_s_setprio(1);
    const int X0 = (2 * l4) ^ swp;
    const u16x4 pa = *(const u16x4*)&sP[w][l15 * 32 + X0 * 4];
    const u16x4 pb = *(const u16x4*)&sP[w][l15 * 32 + (X0 ^ 1) * 4];
    const u16x8 pcat = {pa[0], pa[1], pa[2], pa[3], pb[0], pb[1], pb[2], pb[3]};
    const f16x8 pf = __builtin_bit_cast(f16x8, pcat);
#pragma unroll
    for (int t = 0; t < 4; t++) {
      const f16x8 vf = ldh8(&sV[cur][(t * 16 + l15) * 32 + ((l4 ^ swv) * 8)]);
      acc[t] = MFMA_F16(pf, vf, acc[t]);
    }
    __builtin_amdgcn_s_setprio(0);

    __syncthreads();  // vmcnt(0)+lgkmcnt(0)+barrier: next tile staged & visible
  }

  // deferred denominator: sum the 4 kv-slices (l4 groups) for each q=l15
  lsum += __shfl_xor(lsum, 16);
  lsum += __shfl_xor(lsum, 32);
  // redistribute: epilogue lane needs lsum of q-row (l4*4+r), held by lane (l4*4+r)
  float ls[4];
#pragma unroll
  for (int r = 0; r < 4; r++) ls[r] = __shfl(lsum, l4 * 4 + r);

  // epilogue: out[b][row][h*64+d] = acc/lsum  (acc: row q = l4*4+r, col d = l15)
  const int b = bh >> 4, h = bh & 15;
#pragma unroll
  for (int t = 0; t < 4; t++)
#pragma unroll
    for (int r = 0; r < 4; r++) {
      const int row = q0 + w * 16 + l4 * 4 + r;
      const int d = t * 16 + l15;
      out[(b * 2048 + row) * 1024 + h * 64 + d] = acc[t][r] / ls[r];
    }
}

extern "C" void kernel_launch(void* const* d_in, const int* in_sizes, int n_in,
                              void* d_out, int out_size, void* d_ws, size_t ws_size,
                              hipStream_t stream) {
  const float* z = (const float*)d_in[0];    // [2,2048,1024]
  const float* Wq = (const float*)d_in[1];   // [3072,1024]
  float* out = (float*)d_out;                // [2,2048,1024]

  const long MK = 4096l * 1024;   // z elems
  const long NK = 3072l * 1024;   // W elems
  const long QS = 2l * 16 * 2048 * 64;  // per q/k/v tensor elems

  char* ws = (char*)d_ws;
  unsigned short* zh = (unsigned short*)ws; ws += MK * 2;
  unsigned short* zl = (unsigned short*)ws; ws += MK * 2;
  unsigned short* wh = (unsigned short*)ws; ws += NK * 2;
  unsigned short* qh = (unsigned short*)ws; ws += QS * 2;
  unsigned short* ql = (unsigned short*)ws; ws += QS * 2;
  unsigned short* kk = (unsigned short*)ws; ws += QS * 2;
  unsigned short* vt = (unsigned short*)ws; ws += QS * 2;

  split_kernel<<<(int)(MK / 4 / 256), 256, 0, stream>>>(z, zh, zl, (int)(MK / 4));
  conv_kernel<<<(int)(NK / 4 / 256), 256, 0, stream>>>(Wq, wh, (int)(NK / 4));
  qkv_gemm<<<dim3(32, 24), 256, 0, stream>>>(zh, zl, wh, qh, ql, kk, vt);
  attn_kernel<<<dim3(32, 32), 256, 0, stream>>>(qh, ql, kk, vt, out);
}

// Round 5
// 142.820 us; speedup vs baseline: 1.0262x; 1.0262x over previous
//
#include <hip/hip_runtime.h>
#include <stdint.h>

// MSA fused kernel: qkv = z @ W^T ; split heads ; flash attention ; out fp32.
// R8 -> R9: attention reverted to R7 structure (KVBLK=64; R8's KVBLK=32 halved
// nothing -- grid 1024 = 4 blocks/CU caps occupancy regardless of LDS, and the
// doubled iteration count cost 4us). One surgical change vs R7: sP slot map.
//   R7 map left 2.1M conflict cycles (write map non-bijective per quarter).
//   R8 map halved it (reads still 2-way: lanes l15,l15|1 shared the key).
//   R9: physical 8B slot X = s ^ l15 (s = logical 4-run slot 0..15).
//   Bank-pair = 2X mod 32 -> 16 lanes of a quarter hit 16 distinct pairs on
//   BOTH writes (s=4t+l4) and reads (s=8jf+2l4,+1). PV A-fragment assembled
//   from two ds_read_b64 (X map breaks b128 pair adjacency for odd l15).
//   lsum/acc accumulation orders unchanged -> bit-identical numerics.

typedef _Float16 f16x8 __attribute__((ext_vector_type(8)));
typedef float f32x4 __attribute__((ext_vector_type(4)));
typedef unsigned short u16x8 __attribute__((ext_vector_type(8)));
typedef unsigned short u16x4 __attribute__((ext_vector_type(4)));

#define MFMA_F16(A, B, C) __builtin_amdgcn_mfma_f32_16x16x32_f16((A), (B), (C), 0, 0, 0)

__device__ __forceinline__ unsigned short f2h(float f) {
  _Float16 h = (_Float16)f;  // hw RNE cvt
  return __builtin_bit_cast(unsigned short, h);
}
__device__ __forceinline__ float h2f(unsigned short s) {
  return (float)__builtin_bit_cast(_Float16, s);
}
__device__ __forceinline__ f16x8 ldh8(const unsigned short* p) {
  return __builtin_bit_cast(f16x8, *(const u16x8*)p);
}
// async global->LDS, 16B per lane; dest must be wave-uniform (HW adds lane*16)
__device__ __forceinline__ void lds16(const void* g, void* l) {
  __builtin_amdgcn_global_load_lds((const __attribute__((address_space(1))) void*)g,
                                   (__attribute__((address_space(3))) void*)l,
                                   16, 0, 0);
}

// ---------------- fp32 -> (hi, lo) fp16 split (for z) ----------------
__global__ __launch_bounds__(256) void split_kernel(const float* __restrict__ src,
                                                    unsigned short* __restrict__ hi,
                                                    unsigned short* __restrict__ lo,
                                                    int n4) {
  int i = blockIdx.x * 256 + threadIdx.x;
  if (i >= n4) return;
  const float4 v = reinterpret_cast<const float4*>(src)[i];
  float vv[4] = {v.x, v.y, v.z, v.w};
  unsigned short hh[4], ll[4];
#pragma unroll
  for (int j = 0; j < 4; j++) {
    hh[j] = f2h(vv[j]);
    ll[j] = f2h(vv[j] - h2f(hh[j]));
  }
  u16x4 hv = {hh[0], hh[1], hh[2], hh[3]};
  u16x4 lv = {ll[0], ll[1], ll[2], ll[3]};
  *(u16x4*)&hi[i * 4] = hv;
  *(u16x4*)&lo[i * 4] = lv;
}

// ---------------- fp32 -> fp16 convert (for W, hi only) ----------------
__global__ __launch_bounds__(256) void conv_kernel(const float* __restrict__ src,
                                                   unsigned short* __restrict__ dst,
                                                   int n4) {
  int i = blockIdx.x * 256 + threadIdx.x;
  if (i >= n4) return;
  const float4 v = reinterpret_cast<const float4*>(src)[i];
  u16x4 hv = {f2h(v.x), f2h(v.y), f2h(v.z), f2h(v.w)};
  *(u16x4*)&dst[i * 4] = hv;
}

// ---------------- QKV GEMM: C[4096][3072] = Z @ W^T, scattered epilogue ----------------
// grid (32, 24), 256 threads (4 waves, 2x2, wave-tile 64x64), BK=64.
// LDS tiles [128][64] fp16, XOR chunk-swizzled: 16B-chunk c of row r at (c ^ (r&7)),
// staged via pre-swizzled global source (linear LDS dest).
__global__ __launch_bounds__(256) void qkv_gemm(
    const unsigned short* __restrict__ Ah, const unsigned short* __restrict__ Al,
    const unsigned short* __restrict__ Wh,
    unsigned short* __restrict__ qh, unsigned short* __restrict__ ql,
    unsigned short* __restrict__ kk, unsigned short* __restrict__ vt) {
  __shared__ unsigned short sAh[128 * 64], sAl[128 * 64], sBh[128 * 64];
  const int tid = threadIdx.x;
  const int w = tid >> 6, l = tid & 63;
  const int wr = w >> 1, wc = w & 1;
  const int l15 = l & 15, l4 = l >> 4;
  const int swz = l15 & 7;
  const int bm = blockIdx.x, bn = blockIdx.y;

  f32x4 acc[4][4];
#pragma unroll
  for (int i = 0; i < 4; i++)
#pragma unroll
    for (int j = 0; j < 4; j++) acc[i][j] = (f32x4){0.f, 0.f, 0.f, 0.f};

  for (int k0 = 0; k0 < 1024; k0 += 64) {
    __syncthreads();
#pragma unroll
    for (int c = 0; c < 4; c++) {
      const int chunk = tid + c * 256;          // 0..1023: row = chunk/8, chunk-in-row = chunk%8
      const int row = chunk >> 3, cc = chunk & 7;
      const int scc = cc ^ (row & 7);           // pre-swizzled source chunk
      const int aoff = (bm * 128 + row) * 1024 + k0 + scc * 8;
      const int boff = (bn * 128 + row) * 1024 + k0 + scc * 8;
      const int lo = (w * 64 + c * 256) * 8;    // wave-uniform linear LDS dest
      lds16(Ah + aoff, sAh + lo);
      lds16(Al + aoff, sAl + lo);
      lds16(Wh + boff, sBh + lo);
    }
    __syncthreads();

#pragma unroll
    for (int kh2 = 0; kh2 < 2; kh2++) {
      f16x8 afh[4], afl[4], bfr[4];
#pragma unroll
      for (int i = 0; i < 4; i++) {
        const int off = (wr * 64 + i * 16 + l15) * 64 + ((kh2 * 4 + l4) ^ swz) * 8;
        afh[i] = ldh8(sAh + off);
        afl[i] = ldh8(sAl + off);
      }
#pragma unroll
      for (int j = 0; j < 4; j++) {
        const int off = (wc * 64 + j * 16 + l15) * 64 + ((kh2 * 4 + l4) ^ swz) * 8;
        bfr[j] = ldh8(sBh + off);
      }
      __builtin_amdgcn_s_setprio(1);
#pragma unroll
      for (int i = 0; i < 4; i++)
#pragma unroll
        for (int j = 0; j < 4; j++) {
          acc[i][j] = MFMA_F16(afh[i], bfr[j], acc[i][j]);
          acc[i][j] = MFMA_F16(afl[i], bfr[j], acc[i][j]);
        }
      __builtin_amdgcn_s_setprio(0);
    }
  }

  // epilogue: scatter into q(hi,lo, *0.125*log2e), k(hi), v^T — all fp16
#pragma unroll
  for (int i = 0; i < 4; i++)
#pragma unroll
    for (int j = 0; j < 4; j++)
#pragma unroll
      for (int r = 0; r < 4; r++) {
        float val = acc[i][j][r];
        const int m = bm * 128 + wr * 64 + i * 16 + l4 * 4 + r;
        const int e = bn * 128 + wc * 64 + j * 16 + l15;
        const int b = m >> 11, nidx = m & 2047;
        const int head = e / 192;
        const int rem = e - head * 192;
        const int which = rem >> 6, dh = rem & 63;
        const int bh = b * 16 + head;
        if (which == 0) {
          // 0.125 * log2(e): scores come out in log2 domain -> attn uses exp2
          const float v = val * 0.18033688011112042f;
          const unsigned short h = f2h(v);
          const int o = (bh * 2048 + nidx) * 64 + dh;
          qh[o] = h;
          ql[o] = f2h(v - h2f(h));
        } else if (which == 1) {
          kk[(bh * 2048 + nidx) * 64 + dh] = f2h(val);
        } else {
          vt[(bh * 64 + dh) * 2048 + nidx] = f2h(val);
        }
      }
}

// ---------------- flash attention (no-max softmax, dbuf staging, 16 q-rows/wave) ----
// grid (n/64, b*h) = (32, 32), 256 threads (4 waves); wave w owns q rows
// [q0 + 16w, q0 + 16w + 16). LDS 40 KB, 4 blocks/CU (grid-capped anyway).
// SWAPPED QK^T: S^T = mfma(K, Q) -> lane holds P[q=l15][kv=16t+4*l4+r].
// sP physical slot X = s ^ l15 (s = kv/4): conflict-free write AND read.
__global__ __launch_bounds__(256, 4) void attn_kernel(
    const unsigned short* __restrict__ qh, const unsigned short* __restrict__ ql,
    const unsigned short* __restrict__ kk,
    const unsigned short* __restrict__ vt, float* __restrict__ out) {
  __shared__ unsigned short sK[2][64 * 64], sV[2][64 * 64];
  __shared__ unsigned short sP[4][16 * 64];  // per-wave P tile (16 q x 64 kv)
  const int tid = threadIdx.x, w = tid >> 6, l = tid & 63;
  const int l15 = l & 15, l4 = l >> 4;
  const int swz = l15 & 7;
  const int bh = blockIdx.y;
  const int q0 = blockIdx.x * 64;

  // Q fragments (hi/lo), q pre-scaled by 0.125*log2e
  f16x8 qfh[2], qfl[2];
  {
    const int qrow = (bh * 2048 + q0 + w * 16 + l15) * 64;
#pragma unroll
    for (int kf = 0; kf < 2; kf++) {
      qfh[kf] = ldh8(qh + qrow + kf * 32 + l4 * 8);
      qfl[kf] = ldh8(ql + qrow + kf * 32 + l4 * 8);
    }
  }

  float lsum = 0.f;  // denominator partial for q = l15 (this lane's kv slice)
  f32x4 acc[4];
#pragma unroll
  for (int t = 0; t < 4; t++) acc[t] = (f32x4){0.f, 0.f, 0.f, 0.f};

  const unsigned short* kb = kk + bh * 2048 * 64;
  const unsigned short* vb = vt + bh * 64 * 2048;

  auto STAGE = [&](int bb, int kv0) {
#pragma unroll
    for (int c = 0; c < 2; c++) {
      const int chunk = tid + c * 256;          // 0..511
      const int row = chunk >> 3, cc = chunk & 7;
      const int scc = cc ^ (row & 7);           // pre-swizzled source chunk
      const int lo = (w * 64 + c * 256) * 8;    // wave-uniform linear LDS dest
      lds16(kb + (kv0 + row) * 64 + scc * 8, &sK[bb][lo]);
      lds16(vb + row * 2048 + kv0 + scc * 8, &sV[bb][lo]);
    }
  };

  STAGE(0, 0);
  __syncthreads();

  for (int it = 0; it < 32; ++it) {
    const int cur = it & 1;
    if (it < 31) STAGE(cur ^ 1, (it + 1) * 64);  // prefetch next tile (in flight)

    // S^T = K Q^T (2-term hi/lo): A = K (rows = kv), B = Q (cols = q)
    // lane: q = l15, kv = 16t + 4*l4 + r
    f32x4 s[4];
    __builtin_amdgcn_s_setprio(1);
#pragma unroll
    for (int t = 0; t < 4; t++) {
      f32x4 z0 = (f32x4){0.f, 0.f, 0.f, 0.f};
#pragma unroll
      for (int kf = 0; kf < 2; kf++) {
        const int off = (t * 16 + l15) * 64 + ((kf * 4 + l4) ^ swz) * 8;
        const f16x8 kh8 = ldh8(&sK[cur][off]);
        z0 = MFMA_F16(kh8, qfh[kf], z0);
        z0 = MFMA_F16(kh8, qfl[kf], z0);
      }
      s[t] = z0;
    }
    __builtin_amdgcn_s_setprio(0);

    // softmax-lite: p = exp2(s) (log2e pre-folded), no max-shift, deferred denom.
    // Lane's 4-run t occupies logical 8B slot s = 4t + l4 of row q = l15;
    // physical slot X = s ^ l15 -> 16 distinct bank-pairs per quarter-wave.
#pragma unroll
    for (int t = 0; t < 4; t++) {
      u16x4 pv;
#pragma unroll
      for (int r = 0; r < 4; r++) {
        const float p = __builtin_amdgcn_exp2f(s[t][r]);
        const unsigned short us = f2h(p);
        pv[r] = us;
        lsum += h2f(us);  // denominator consistent with rounded numerator
      }
      const int X = (4 * t + l4) ^ l15;
      *(u16x4*)&sP[w][l15 * 64 + X * 4] = pv;
    }

    // PV: O += P @ V. A-fragment jf: k-elems = kv 32*jf + 8*l4 + 0..7
    // = logical slots s0 = 8*jf + 2*l4 and s0^1; read as two b64 (X map
    // breaks b128 adjacency for odd l15), concat in logical order.
    __builtin_amdgcn_s_setprio(1);
    f16x8 pf[2];
#pragma unroll
    for (int jf = 0; jf < 2; jf++) {
      const int s0 = 8 * jf + 2 * l4;
      const u16x4 pa = *(const u16x4*)&sP[w][l15 * 64 + (s0 ^ l15) * 4];
      const u16x4 pb = *(const u16x4*)&sP[w][l15 * 64 + ((s0 ^ 1) ^ l15) * 4];
      const u16x8 pcat = {pa[0], pa[1], pa[2], pa[3], pb[0], pb[1], pb[2], pb[3]};
      pf[jf] = __builtin_bit_cast(f16x8, pcat);
    }
#pragma unroll
    for (int t = 0; t < 4; t++)
#pragma unroll
      for (int jf = 0; jf < 2; jf++) {
        const f16x8 vf = ldh8(&sV[cur][(t * 16 + l15) * 64 + ((jf * 4 + l4) ^ swz) * 8]);
        acc[t] = MFMA_F16(pf[jf], vf, acc[t]);
      }
    __builtin_amdgcn_s_setprio(0);

    __syncthreads();  // vmcnt(0)+lgkmcnt(0)+barrier: next tile staged & visible
  }

  // deferred denominator: sum the 4 kv-slices (l4 groups) for each q=l15
  lsum += __shfl_xor(lsum, 16);
  lsum += __shfl_xor(lsum, 32);
  // redistribute: epilogue lane needs lsum of q-row (l4*4+r), held by lane (l4*4+r)
  float ls[4];
#pragma unroll
  for (int r = 0; r < 4; r++) ls[r] = __shfl(lsum, l4 * 4 + r);

  // epilogue: out[b][row][h*64+d] = acc/lsum  (acc: row q = l4*4+r, col d = l15)
  const int b = bh >> 4, h = bh & 15;
#pragma unroll
  for (int t = 0; t < 4; t++)
#pragma unroll
    for (int r = 0; r < 4; r++) {
      const int row = q0 + w * 16 + l4 * 4 + r;
      const int d = t * 16 + l15;
      out[(b * 2048 + row) * 1024 + h * 64 + d] = acc[t][r] / ls[r];
    }
}

extern "C" void kernel_launch(void* const* d_in, const int* in_sizes, int n_in,
                              void* d_out, int out_size, void* d_ws, size_t ws_size,
                              hipStream_t stream) {
  const float* z = (const float*)d_in[0];    // [2,2048,1024]
  const float* Wq = (const float*)d_in[1];   // [3072,1024]
  float* out = (float*)d_out;                // [2,2048,1024]

  const long MK = 4096l * 1024;   // z elems
  const long NK = 3072l * 1024;   // W elems
  const long QS = 2l * 16 * 2048 * 64;  // per q/k/v tensor elems

  char* ws = (char*)d_ws;
  unsigned short* zh = (unsigned short*)ws; ws += MK * 2;
  unsigned short* zl = (unsigned short*)ws; ws += MK * 2;
  unsigned short* wh = (unsigned short*)ws; ws += NK * 2;
  unsigned short* qh = (unsigned short*)ws; ws += QS * 2;
  unsigned short* ql = (unsigned short*)ws; ws += QS * 2;
  unsigned short* kk = (unsigned short*)ws; ws += QS * 2;
  unsigned short* vt = (unsigned short*)ws; ws += QS * 2;

  split_kernel<<<(int)(MK / 4 / 256), 256, 0, stream>>>(z, zh, zl, (int)(MK / 4));
  conv_kernel<<<(int)(NK / 4 / 256), 256, 0, stream>>>(Wq, wh, (int)(NK / 4));
  qkv_gemm<<<dim3(32, 24), 256, 0, stream>>>(zh, zl, wh, qh, ql, kk, vt);
  attn_kernel<<<dim3(32, 32), 256, 0, stream>>>(qh, ql, kk, vt, out);
}

// Round 6
// 134.979 us; speedup vs baseline: 1.0858x; 1.0581x over previous
//
#include <hip/hip_runtime.h>
#include <stdint.h>

// MSA fused kernel: qkv = z @ W^T ; split heads ; flash attention ; out fp32.
// R9 -> R10 (attention only): VALU diet. rocprof showed ~300 VALU inst per
// wave-iteration (2x the source requirement); the excess is runtime-`cur`
// double-buffer addressing regenerated every iteration, plus 16 h2f/iter
// for the "rounded denominator".
//  (a) kv loop unrolled x2 with compile-time cur (always_inline lambda called
//      with literals): all sK/sV offsets become static bases, addr chains hoisted.
//  (b) lsum accumulates fp32 p (pre-rounding): denominator shift ~3e-6 relative
//      (mean-zero RNE residue), removes 16 v_cvt_f32_f16 per iteration.
// R9's conflict post-mortem: residual 1.05M = 8 cyc/iter tracks the 16 sK/sV
// ds_read_b128 per iter (~0.5 cyc each, benign swizzle residue); sP is clean.

typedef _Float16 f16x8 __attribute__((ext_vector_type(8)));
typedef float f32x4 __attribute__((ext_vector_type(4)));
typedef unsigned short u16x8 __attribute__((ext_vector_type(8)));
typedef unsigned short u16x4 __attribute__((ext_vector_type(4)));

#define MFMA_F16(A, B, C) __builtin_amdgcn_mfma_f32_16x16x32_f16((A), (B), (C), 0, 0, 0)

__device__ __forceinline__ unsigned short f2h(float f) {
  _Float16 h = (_Float16)f;  // hw RNE cvt
  return __builtin_bit_cast(unsigned short, h);
}
__device__ __forceinline__ float h2f(unsigned short s) {
  return (float)__builtin_bit_cast(_Float16, s);
}
__device__ __forceinline__ f16x8 ldh8(const unsigned short* p) {
  return __builtin_bit_cast(f16x8, *(const u16x8*)p);
}
// async global->LDS, 16B per lane; dest must be wave-uniform (HW adds lane*16)
__device__ __forceinline__ void lds16(const void* g, void* l) {
  __builtin_amdgcn_global_load_lds((const __attribute__((address_space(1))) void*)g,
                                   (__attribute__((address_space(3))) void*)l,
                                   16, 0, 0);
}

// ---------------- fp32 -> (hi, lo) fp16 split (for z) ----------------
__global__ __launch_bounds__(256) void split_kernel(const float* __restrict__ src,
                                                    unsigned short* __restrict__ hi,
                                                    unsigned short* __restrict__ lo,
                                                    int n4) {
  int i = blockIdx.x * 256 + threadIdx.x;
  if (i >= n4) return;
  const float4 v = reinterpret_cast<const float4*>(src)[i];
  float vv[4] = {v.x, v.y, v.z, v.w};
  unsigned short hh[4], ll[4];
#pragma unroll
  for (int j = 0; j < 4; j++) {
    hh[j] = f2h(vv[j]);
    ll[j] = f2h(vv[j] - h2f(hh[j]));
  }
  u16x4 hv = {hh[0], hh[1], hh[2], hh[3]};
  u16x4 lv = {ll[0], ll[1], ll[2], ll[3]};
  *(u16x4*)&hi[i * 4] = hv;
  *(u16x4*)&lo[i * 4] = lv;
}

// ---------------- fp32 -> fp16 convert (for W, hi only) ----------------
__global__ __launch_bounds__(256) void conv_kernel(const float* __restrict__ src,
                                                   unsigned short* __restrict__ dst,
                                                   int n4) {
  int i = blockIdx.x * 256 + threadIdx.x;
  if (i >= n4) return;
  const float4 v = reinterpret_cast<const float4*>(src)[i];
  u16x4 hv = {f2h(v.x), f2h(v.y), f2h(v.z), f2h(v.w)};
  *(u16x4*)&dst[i * 4] = hv;
}

// ---------------- QKV GEMM: C[4096][3072] = Z @ W^T, scattered epilogue ----------------
// grid (32, 24), 256 threads (4 waves, 2x2, wave-tile 64x64), BK=64.
// LDS tiles [128][64] fp16, XOR chunk-swizzled: 16B-chunk c of row r at (c ^ (r&7)),
// staged via pre-swizzled global source (linear LDS dest).
__global__ __launch_bounds__(256) void qkv_gemm(
    const unsigned short* __restrict__ Ah, const unsigned short* __restrict__ Al,
    const unsigned short* __restrict__ Wh,
    unsigned short* __restrict__ qh, unsigned short* __restrict__ ql,
    unsigned short* __restrict__ kk, unsigned short* __restrict__ vt) {
  __shared__ unsigned short sAh[128 * 64], sAl[128 * 64], sBh[128 * 64];
  const int tid = threadIdx.x;
  const int w = tid >> 6, l = tid & 63;
  const int wr = w >> 1, wc = w & 1;
  const int l15 = l & 15, l4 = l >> 4;
  const int swz = l15 & 7;
  const int bm = blockIdx.x, bn = blockIdx.y;

  f32x4 acc[4][4];
#pragma unroll
  for (int i = 0; i < 4; i++)
#pragma unroll
    for (int j = 0; j < 4; j++) acc[i][j] = (f32x4){0.f, 0.f, 0.f, 0.f};

  for (int k0 = 0; k0 < 1024; k0 += 64) {
    __syncthreads();
#pragma unroll
    for (int c = 0; c < 4; c++) {
      const int chunk = tid + c * 256;          // 0..1023: row = chunk/8, chunk-in-row = chunk%8
      const int row = chunk >> 3, cc = chunk & 7;
      const int scc = cc ^ (row & 7);           // pre-swizzled source chunk
      const int aoff = (bm * 128 + row) * 1024 + k0 + scc * 8;
      const int boff = (bn * 128 + row) * 1024 + k0 + scc * 8;
      const int lo = (w * 64 + c * 256) * 8;    // wave-uniform linear LDS dest
      lds16(Ah + aoff, sAh + lo);
      lds16(Al + aoff, sAl + lo);
      lds16(Wh + boff, sBh + lo);
    }
    __syncthreads();

#pragma unroll
    for (int kh2 = 0; kh2 < 2; kh2++) {
      f16x8 afh[4], afl[4], bfr[4];
#pragma unroll
      for (int i = 0; i < 4; i++) {
        const int off = (wr * 64 + i * 16 + l15) * 64 + ((kh2 * 4 + l4) ^ swz) * 8;
        afh[i] = ldh8(sAh + off);
        afl[i] = ldh8(sAl + off);
      }
#pragma unroll
      for (int j = 0; j < 4; j++) {
        const int off = (wc * 64 + j * 16 + l15) * 64 + ((kh2 * 4 + l4) ^ swz) * 8;
        bfr[j] = ldh8(sBh + off);
      }
      __builtin_amdgcn_s_setprio(1);
#pragma unroll
      for (int i = 0; i < 4; i++)
#pragma unroll
        for (int j = 0; j < 4; j++) {
          acc[i][j] = MFMA_F16(afh[i], bfr[j], acc[i][j]);
          acc[i][j] = MFMA_F16(afl[i], bfr[j], acc[i][j]);
        }
      __builtin_amdgcn_s_setprio(0);
    }
  }

  // epilogue: scatter into q(hi,lo, *0.125*log2e), k(hi), v^T — all fp16
#pragma unroll
  for (int i = 0; i < 4; i++)
#pragma unroll
    for (int j = 0; j < 4; j++)
#pragma unroll
      for (int r = 0; r < 4; r++) {
        float val = acc[i][j][r];
        const int m = bm * 128 + wr * 64 + i * 16 + l4 * 4 + r;
        const int e = bn * 128 + wc * 64 + j * 16 + l15;
        const int b = m >> 11, nidx = m & 2047;
        const int head = e / 192;
        const int rem = e - head * 192;
        const int which = rem >> 6, dh = rem & 63;
        const int bh = b * 16 + head;
        if (which == 0) {
          // 0.125 * log2(e): scores come out in log2 domain -> attn uses exp2
          const float v = val * 0.18033688011112042f;
          const unsigned short h = f2h(v);
          const int o = (bh * 2048 + nidx) * 64 + dh;
          qh[o] = h;
          ql[o] = f2h(v - h2f(h));
        } else if (which == 1) {
          kk[(bh * 2048 + nidx) * 64 + dh] = f2h(val);
        } else {
          vt[(bh * 64 + dh) * 2048 + nidx] = f2h(val);
        }
      }
}

// ---------------- flash attention (no-max softmax, dbuf staging, 16 q-rows/wave) ----
// grid (n/64, b*h) = (32, 32), 256 threads (4 waves); wave w owns q rows
// [q0 + 16w, q0 + 16w + 16). LDS 40 KB, 4 blocks/CU (grid-capped anyway).
// SWAPPED QK^T: S^T = mfma(K, Q) -> lane holds P[q=l15][kv=16t+4*l4+r].
// sP physical slot X = s ^ l15 (s = kv/4): conflict-free write AND read.
// kv loop unrolled x2: compile-time double-buffer index.
__global__ __launch_bounds__(256, 4) void attn_kernel(
    const unsigned short* __restrict__ qh, const unsigned short* __restrict__ ql,
    const unsigned short* __restrict__ kk,
    const unsigned short* __restrict__ vt, float* __restrict__ out) {
  __shared__ unsigned short sK[2][64 * 64], sV[2][64 * 64];
  __shared__ unsigned short sP[4][16 * 64];  // per-wave P tile (16 q x 64 kv)
  const int tid = threadIdx.x, w = tid >> 6, l = tid & 63;
  const int l15 = l & 15, l4 = l >> 4;
  const int swz = l15 & 7;
  const int bh = blockIdx.y;
  const int q0 = blockIdx.x * 64;

  // Q fragments (hi/lo), q pre-scaled by 0.125*log2e
  f16x8 qfh[2], qfl[2];
  {
    const int qrow = (bh * 2048 + q0 + w * 16 + l15) * 64;
#pragma unroll
    for (int kf = 0; kf < 2; kf++) {
      qfh[kf] = ldh8(qh + qrow + kf * 32 + l4 * 8);
      qfl[kf] = ldh8(ql + qrow + kf * 32 + l4 * 8);
    }
  }

  float lsum = 0.f;  // denominator partial for q = l15 (this lane's kv slice)
  f32x4 acc[4];
#pragma unroll
  for (int t = 0; t < 4; t++) acc[t] = (f32x4){0.f, 0.f, 0.f, 0.f};

  const unsigned short* kb = kk + bh * 2048 * 64;
  const unsigned short* vb = vt + bh * 64 * 2048;

  auto STAGE = [&](int bb, int kv0) __attribute__((always_inline)) {
#pragma unroll
    for (int c = 0; c < 2; c++) {
      const int chunk = tid + c * 256;          // 0..511
      const int row = chunk >> 3, cc = chunk & 7;
      const int scc = cc ^ (row & 7);           // pre-swizzled source chunk
      const int lo = (w * 64 + c * 256) * 8;    // wave-uniform linear LDS dest
      lds16(kb + (kv0 + row) * 64 + scc * 8, &sK[bb][lo]);
      lds16(vb + row * 2048 + kv0 + scc * 8, &sV[bb][lo]);
    }
  };

  STAGE(0, 0);
  __syncthreads();

  // one kv tile; cur MUST be a literal so all LDS addressing is static
  auto body = [&](const int cur, const bool pfetch, const int nkv)
      __attribute__((always_inline)) {
    if (pfetch) STAGE(cur ^ 1, nkv);  // prefetch next tile (in flight)

    // S^T = K Q^T (2-term hi/lo): lane: q = l15, kv = 16t + 4*l4 + r
    f32x4 s[4];
    __builtin_amdgcn_s_setprio(1);
#pragma unroll
    for (int t = 0; t < 4; t++) {
      f32x4 z0 = (f32x4){0.f, 0.f, 0.f, 0.f};
#pragma unroll
      for (int kf = 0; kf < 2; kf++) {
        const int off = (t * 16 + l15) * 64 + ((kf * 4 + l4) ^ swz) * 8;
        const f16x8 kh8 = ldh8(&sK[cur][off]);
        z0 = MFMA_F16(kh8, qfh[kf], z0);
        z0 = MFMA_F16(kh8, qfl[kf], z0);
      }
      s[t] = z0;
    }
    __builtin_amdgcn_s_setprio(0);

    // softmax-lite: p = exp2(s); fp32 lsum (denominator rounding residue ~3e-6)
#pragma unroll
    for (int t = 0; t < 4; t++) {
      u16x4 pv;
#pragma unroll
      for (int r = 0; r < 4; r++) {
        const float p = __builtin_amdgcn_exp2f(s[t][r]);
        lsum += p;
        pv[r] = f2h(p);
      }
      const int X = (4 * t + l4) ^ l15;
      *(u16x4*)&sP[w][l15 * 64 + X * 4] = pv;
    }

    // PV: O += P @ V  (A-fragment from two b64 reads at slots s0^l15, (s0^1)^l15)
    __builtin_amdgcn_s_setprio(1);
    f16x8 pf[2];
#pragma unroll
    for (int jf = 0; jf < 2; jf++) {
      const int s0 = 8 * jf + 2 * l4;
      const u16x4 pa = *(const u16x4*)&sP[w][l15 * 64 + (s0 ^ l15) * 4];
      const u16x4 pb = *(const u16x4*)&sP[w][l15 * 64 + ((s0 ^ 1) ^ l15) * 4];
      const u16x8 pcat = {pa[0], pa[1], pa[2], pa[3], pb[0], pb[1], pb[2], pb[3]};
      pf[jf] = __builtin_bit_cast(f16x8, pcat);
    }
#pragma unroll
    for (int t = 0; t < 4; t++)
#pragma unroll
      for (int jf = 0; jf < 2; jf++) {
        const f16x8 vf = ldh8(&sV[cur][(t * 16 + l15) * 64 + ((jf * 4 + l4) ^ swz) * 8]);
        acc[t] = MFMA_F16(pf[jf], vf, acc[t]);
      }
    __builtin_amdgcn_s_setprio(0);

    __syncthreads();  // vmcnt(0)+lgkmcnt(0)+barrier: next tile staged & visible
  };

#pragma unroll 1
  for (int it2 = 0; it2 < 16; ++it2) {
    body(0, true, it2 * 128 + 64);        // tile 2*it2   (buf 0), prefetch odd
    body(1, it2 < 15, it2 * 128 + 128);   // tile 2*it2+1 (buf 1), prefetch even
  }

  // deferred denominator: sum the 4 kv-slices (l4 groups) for each q=l15
  lsum += __shfl_xor(lsum, 16);
  lsum += __shfl_xor(lsum, 32);
  // redistribute: epilogue lane needs lsum of q-row (l4*4+r), held by lane (l4*4+r)
  float ls[4];
#pragma unroll
  for (int r = 0; r < 4; r++) ls[r] = __shfl(lsum, l4 * 4 + r);

  // epilogue: out[b][row][h*64+d] = acc/lsum  (acc: row q = l4*4+r, col d = l15)
  const int b = bh >> 4, h = bh & 15;
#pragma unroll
  for (int t = 0; t < 4; t++)
#pragma unroll
    for (int r = 0; r < 4; r++) {
      const int row = q0 + w * 16 + l4 * 4 + r;
      const int d = t * 16 + l15;
      out[(b * 2048 + row) * 1024 + h * 64 + d] = acc[t][r] / ls[r];
    }
}

extern "C" void kernel_launch(void* const* d_in, const int* in_sizes, int n_in,
                              void* d_out, int out_size, void* d_ws, size_t ws_size,
                              hipStream_t stream) {
  const float* z = (const float*)d_in[0];    // [2,2048,1024]
  const float* Wq = (const float*)d_in[1];   // [3072,1024]
  float* out = (float*)d_out;                // [2,2048,1024]

  const long MK = 4096l * 1024;   // z elems
  const long NK = 3072l * 1024;   // W elems
  const long QS = 2l * 16 * 2048 * 64;  // per q/k/v tensor elems

  char* ws = (char*)d_ws;
  unsigned short* zh = (unsigned short*)ws; ws += MK * 2;
  unsigned short* zl = (unsigned short*)ws; ws += MK * 2;
  unsigned short* wh = (unsigned short*)ws; ws += NK * 2;
  unsigned short* qh = (unsigned short*)ws; ws += QS * 2;
  unsigned short* ql = (unsigned short*)ws; ws += QS * 2;
  unsigned short* kk = (unsigned short*)ws; ws += QS * 2;
  unsigned short* vt = (unsigned short*)ws; ws += QS * 2;

  split_kernel<<<(int)(MK / 4 / 256), 256, 0, stream>>>(z, zh, zl, (int)(MK / 4));
  conv_kernel<<<(int)(NK / 4 / 256), 256, 0, stream>>>(Wq, wh, (int)(NK / 4));
  qkv_gemm<<<dim3(32, 24), 256, 0, stream>>>(zh, zl, wh, qh, ql, kk, vt);
  attn_kernel<<<dim3(32, 32), 256, 0, stream>>>(qh, ql, kk, vt, out);
}